// Round 1
// baseline (280.138 us; speedup 1.0000x reference)
//
#include <hip/hip_runtime.h>

#define PI_F 3.14159265358979323846f

constexpr int N_COLS   = 16384;   // row length
constexpr int HALF     = 8192;    // N/2 : half-size complex FFT length
constexpr int NTHREADS = 1024;

// One block per row. Algorithm:
//   V_k = (x_k - j x_{N-k}) e^{j pi k/(2N)}   (Hermitian, V_0 = x_0)
//   P = unnormalized IDFT_N(V)  (real);  y_{2m} = (P_m + x0)/2, y_{2m+1} = (P_{N-1-m}+x0)/2
//   Half-size packing: z_n = P_{2n} + j P_{2n+1} = IDFT_H(Z),
//     Z_k = (V_k + V_{k+H}) + j e^{j 2 pi k/N} (V_k - V_{k+H})
//   8192-pt complex IDFT in LDS: bit-reversed input scatter + 13 DIT stages
//   (fused as 6 radix-4 passes + 1 radix-2 pass).
__global__ __launch_bounds__(NTHREADS)
void idxct_kernel(const float* __restrict__ x,
                  const float* __restrict__ expk,
                  float* __restrict__ y)
{
    __shared__ float sre[HALF];
    __shared__ float sim[HALF];

    const int row = blockIdx.x;
    const float* __restrict__ xr = x + (size_t)row * N_COLS;
    float* __restrict__ yr       = y + (size_t)row * N_COLS;
    const int t = threadIdx.x;
    const float x0 = xr[0];
    const float2* __restrict__ ek2 = (const float2*)expk;

    // ---- preprocess: Z_k -> LDS[bitrev13(k)] ----
    #pragma unroll
    for (int i = 0; i < HALF / NTHREADS; ++i) {
        int k = t + i * NTHREADS;
        float vkr, vki;
        {
            float2 e = ek2[k];
            float c = e.x, s = -e.y;          // e^{+j pi k/(2N)}
            if (k == 0) { vkr = x0; vki = 0.0f; }
            else {
                float a = xr[k], b = xr[N_COLS - k];
                vkr = a * c + b * s;          // (a - j b)(c + j s)
                vki = a * s - b * c;
            }
        }
        float wkr, wki;                        // V_{k+H}
        {
            int K = k + HALF;
            float2 e = ek2[K];
            float c = e.x, s = -e.y;
            float a = xr[K], b = xr[N_COLS - K];
            wkr = a * c + b * s;
            wki = a * s - b * c;
        }
        float dr = vkr - wkr, di = vki - wki;
        float ang = (2.0f * PI_F / (float)N_COLS) * (float)k;
        float es, ec;
        __sincosf(ang, &es, &ec);              // sin, cos
        // Z = (V+W) + j*(ec + j es)*(dr + j di)
        float zr = (vkr + wkr) - (ec * di + es * dr);
        float zi = (vki + wki) + (ec * dr - es * di);
        int rk = (int)(__brev((unsigned)k) >> 19);   // 13-bit reverse
        sre[rk] = zr;
        sim[rk] = zi;
    }

    // ---- 13 DIT stages (positive exponent / inverse), 6 fused radix-4 passes ----
    #pragma unroll
    for (int p = 0; p < 6; ++p) {
        const int s  = 1 << (2 * p);           // 1,4,16,64,256,1024
        __syncthreads();
        #pragma unroll
        for (int u = 0; u < 2; ++u) {
            int q   = t + u * NTHREADS;        // quad id 0..2047
            int j   = q & (s - 1);
            int base = ((q >> (2 * p)) << (2 * p + 2)) + j;
            float r0 = sre[base],           i0 = sim[base];
            float r1 = sre[base + s],       i1 = sim[base + s];
            float r2 = sre[base + 2 * s],   i2 = sim[base + 2 * s];
            float r3 = sre[base + 3 * s],   i3 = sim[base + 3 * s];
            // stage s twiddle: w1 = e^{+j pi j / s}
            float a1 = (float)j * (PI_F / (float)s);
            float s1, c1; __sincosf(a1, &s1, &c1);
            // stage 2s twiddle: w2 = e^{+j pi j / (2s)}; pair (1,3) uses j*w2
            float a2 = (float)j * (PI_F / (float)(2 * s));
            float s2, c2; __sincosf(a2, &s2, &c2);
            float tr, ti;
            tr = c1 * r1 - s1 * i1; ti = c1 * i1 + s1 * r1;
            r1 = r0 - tr; i1 = i0 - ti; r0 += tr; i0 += ti;
            tr = c1 * r3 - s1 * i3; ti = c1 * i3 + s1 * r3;
            r3 = r2 - tr; i3 = i2 - ti; r2 += tr; i2 += ti;
            tr = c2 * r2 - s2 * i2; ti = c2 * i2 + s2 * r2;
            r2 = r0 - tr; i2 = i0 - ti; r0 += tr; i0 += ti;
            tr = -s2 * r3 - c2 * i3; ti = c2 * r3 - s2 * i3;   // (j*w2)*e3
            r3 = r1 - tr; i3 = i1 - ti; r1 += tr; i1 += ti;
            sre[base]         = r0; sim[base]         = i0;
            sre[base + s]     = r1; sim[base + s]     = i1;
            sre[base + 2 * s] = r2; sim[base + 2 * s] = i2;
            sre[base + 3 * s] = r3; sim[base + 3 * s] = i3;
        }
    }

    // ---- final radix-2 stage, span 4096 ----
    __syncthreads();
    #pragma unroll
    for (int u = 0; u < 4; ++u) {
        int q = t + u * NTHREADS;              // 0..4095
        float a = (float)q * (PI_F / 4096.0f);
        float sn, cs; __sincosf(a, &sn, &cs);
        float r0 = sre[q],        i0 = sim[q];
        float r1 = sre[q + 4096], i1 = sim[q + 4096];
        float tr = cs * r1 - sn * i1;
        float ti = cs * i1 + sn * r1;
        sre[q]        = r0 + tr; sim[q]        = i0 + ti;
        sre[q + 4096] = r0 - tr; sim[q + 4096] = i0 - ti;
    }
    __syncthreads();

    // ---- epilogue: y_q from z (natural order in LDS), coalesced writes ----
    #pragma unroll
    for (int i = 0; i < N_COLS / NTHREADS; ++i) {
        int q = t + i * NTHREADS;
        int pidx = (q & 1) ? (N_COLS - 1 - (q >> 1)) : (q >> 1);
        int zi = pidx >> 1;
        float val = (pidx & 1) ? sim[zi] : sre[zi];
        yr[q] = 0.5f * (val + x0);
    }
}

extern "C" void kernel_launch(void* const* d_in, const int* in_sizes, int n_in,
                              void* d_out, int out_size, void* d_ws, size_t ws_size,
                              hipStream_t stream)
{
    const float* x    = (const float*)d_in[0];
    const float* expk = (const float*)d_in[1];
    float* y          = (float*)d_out;
    const int M = in_sizes[0] / N_COLS;        // 2048 rows
    idxct_kernel<<<dim3(M), dim3(NTHREADS), 0, stream>>>(x, expk, y);
}

// Round 3
// 257.217 us; speedup vs baseline: 1.0891x; 1.0891x over previous
//
#include <hip/hip_runtime.h>

#define PI_F 3.14159265358979323846f

constexpr int N_COLS   = 16384;   // row length
constexpr int HALF     = 8192;    // N/2 : half-size complex FFT length
constexpr int NTHREADS = 1024;

// Bank swizzle: folds address bits 5..12 into bits 0..4. Bijective on [0,8192).
// Makes the bit-reversed scatter and the stride-4 pass conflict-free (2-way),
// caps everything else at <=4-way (was up to 64-way).
// NOTE: for base with low-2 bits clear and c in 0..3: sw(base+c) = sw(base) ^ c
// (XOR, not +: the mask XORs into bits 0..1, so adding c could carry).
__device__ __forceinline__ int sw(int a) {
    return a ^ ((a >> 5) & 31) ^ ((a >> 10) & 31);
}

// One block per row. Algorithm:
//   V_k = (x_k - j x_{N-k}) e^{j pi k/(2N)}   (Hermitian, V_0 = x_0)
//   P = unnormalized IDFT_N(V)  (real);  y_{2m} = (P_m + x0)/2, y_{2m+1} = (P_{N-1-m}+x0)/2
//   Half-size packing: Z_k = (V_k + V_{k+H}) + j e^{j 2 pi k/N} (V_k - V_{k+H})
//   8192-pt complex IDFT in LDS: bit-reversed scatter + 6 radix-4 + 1 radix-2 passes.
__global__ __launch_bounds__(NTHREADS)
void idxct_kernel(const float* __restrict__ x,
                  const float* __restrict__ expk,
                  float* __restrict__ y)
{
    __shared__ float sre[HALF];
    __shared__ float sim[HALF];

    const int row = blockIdx.x;
    const float* __restrict__ xr = x + (size_t)row * N_COLS;
    float* __restrict__ yr       = y + (size_t)row * N_COLS;
    const int t = threadIdx.x;
    const float x0 = xr[0];
    const float2* __restrict__ ek2 = (const float2*)expk;

    // ---- preprocess: Z_k -> LDS[sw(bitrev13(k))] ----
    #pragma unroll
    for (int i = 0; i < HALF / NTHREADS; ++i) {
        int k = t + i * NTHREADS;
        float vkr, vki, c0, s0;
        {
            float2 e = ek2[k];
            c0 = e.x; s0 = -e.y;               // e^{+j pi k/(2N)}
            if (k == 0) { vkr = x0; vki = 0.0f; }
            else {
                float a = xr[k], b = xr[N_COLS - k];
                vkr = a * c0 + b * s0;         // (a - j b)(c + j s)
                vki = a * s0 - b * c0;
            }
        }
        float wkr, wki;                        // V_{k+H}
        {
            int K = k + HALF;
            float2 e = ek2[K];
            float c = e.x, s = -e.y;
            float a = xr[K], b = xr[N_COLS - K];
            wkr = a * c + b * s;
            wki = a * s - b * c;
        }
        float dr = vkr - wkr, di = vki - wki;
        // e^{j 2 pi k / N} = (c0 + j s0)^4  (two complex squarings, no sincos)
        float cA = c0 * c0 - s0 * s0, sA = 2.0f * c0 * s0;
        float ec = cA * cA - sA * sA, es = 2.0f * cA * sA;
        // Z = (V+W) + j*(ec + j es)*(dr + j di)
        float zr = (vkr + wkr) - (ec * di + es * dr);
        float zi = (vki + wki) + (ec * dr - es * di);
        int rk = (int)(__brev((unsigned)k) >> 19);   // 13-bit reverse
        int pa = sw(rk);
        sre[pa] = zr;
        sim[pa] = zi;
    }

    // ---- pass p=0 (s=1): twiddles are all 1 — pure butterflies ----
    __syncthreads();
    #pragma unroll
    for (int u = 0; u < 2; ++u) {
        int q = t + u * NTHREADS;
        int a0 = sw(q << 2);                   // base low-2 bits clear:
        int a1 = a0 ^ 1, a2i = a0 ^ 2, a3 = a0 ^ 3;  // sw(base+c) = sw(base)^c
        float r0 = sre[a0],  i0 = sim[a0];
        float r1 = sre[a1],  i1 = sim[a1];
        float r2 = sre[a2i], i2 = sim[a2i];
        float r3 = sre[a3],  i3 = sim[a3];
        float tr, ti;
        tr = r1;  ti = i1;  r1 = r0 - tr; i1 = i0 - ti; r0 += tr; i0 += ti;
        tr = r3;  ti = i3;  r3 = r2 - tr; i3 = i2 - ti; r2 += tr; i2 += ti;
        tr = r2;  ti = i2;  r2 = r0 - tr; i2 = i0 - ti; r0 += tr; i0 += ti;
        tr = -i3; ti = r3;  r3 = r1 - tr; i3 = i1 - ti; r1 += tr; i1 += ti;
        sre[a0]  = r0; sim[a0]  = i0;
        sre[a1]  = r1; sim[a1]  = i1;
        sre[a2i] = r2; sim[a2i] = i2;
        sre[a3]  = r3; sim[a3]  = i3;
    }

    // ---- passes p=1..5 (s=4..1024): one sincos, w1 = w2^2 ----
    #pragma unroll
    for (int p = 1; p < 6; ++p) {
        const int s = 1 << (2 * p);
        __syncthreads();
        #pragma unroll
        for (int u = 0; u < 2; ++u) {
            int q = t + u * NTHREADS;
            int j = q & (s - 1);
            int base = ((q >> (2 * p)) << (2 * p + 2)) + j;
            int a0 = sw(base);
            int a1 = sw(base + s);
            int a2i = sw(base + 2 * s);
            int a3 = sw(base + 3 * s);
            float r0 = sre[a0],  i0 = sim[a0];
            float r1 = sre[a1],  i1 = sim[a1];
            float r2 = sre[a2i], i2 = sim[a2i];
            float r3 = sre[a3],  i3 = sim[a3];
            // w2 = e^{+j pi j/(2s)}; w1 = w2^2 = e^{+j pi j/s}
            float a2ang = (float)j * (PI_F / (float)(2 * s));
            float s2, c2; __sincosf(a2ang, &s2, &c2);
            float c1 = c2 * c2 - s2 * s2;
            float s1 = 2.0f * c2 * s2;
            float tr, ti;
            tr = c1 * r1 - s1 * i1; ti = c1 * i1 + s1 * r1;
            r1 = r0 - tr; i1 = i0 - ti; r0 += tr; i0 += ti;
            tr = c1 * r3 - s1 * i3; ti = c1 * i3 + s1 * r3;
            r3 = r2 - tr; i3 = i2 - ti; r2 += tr; i2 += ti;
            tr = c2 * r2 - s2 * i2; ti = c2 * i2 + s2 * r2;
            r2 = r0 - tr; i2 = i0 - ti; r0 += tr; i0 += ti;
            tr = -s2 * r3 - c2 * i3; ti = c2 * r3 - s2 * i3;   // (j*w2)*e3
            r3 = r1 - tr; i3 = i1 - ti; r1 += tr; i1 += ti;
            sre[a0]  = r0; sim[a0]  = i0;
            sre[a1]  = r1; sim[a1]  = i1;
            sre[a2i] = r2; sim[a2i] = i2;
            sre[a3]  = r3; sim[a3]  = i3;
        }
    }

    // ---- final radix-2 stage, span 4096 ----
    __syncthreads();
    #pragma unroll
    for (int u = 0; u < 4; ++u) {
        int q = t + u * NTHREADS;              // 0..4095
        float a = (float)q * (PI_F / 4096.0f);
        float sn, cs; __sincosf(a, &sn, &cs);
        int a0 = sw(q);
        int a1 = sw(q + 4096);
        float r0 = sre[a0], i0 = sim[a0];
        float r1 = sre[a1], i1 = sim[a1];
        float tr = cs * r1 - sn * i1;
        float ti = cs * i1 + sn * r1;
        sre[a0] = r0 + tr; sim[a0] = i0 + ti;
        sre[a1] = r0 - tr; sim[a1] = i0 - ti;
    }
    __syncthreads();

    // ---- epilogue: y_q from z (natural order in LDS), coalesced writes ----
    #pragma unroll
    for (int i = 0; i < N_COLS / NTHREADS; ++i) {
        int q = t + i * NTHREADS;
        int pidx = (q & 1) ? (N_COLS - 1 - (q >> 1)) : (q >> 1);
        int zi = sw(pidx >> 1);
        float val = (pidx & 1) ? sim[zi] : sre[zi];
        yr[q] = 0.5f * (val + x0);
    }
}

extern "C" void kernel_launch(void* const* d_in, const int* in_sizes, int n_in,
                              void* d_out, int out_size, void* d_ws, size_t ws_size,
                              hipStream_t stream)
{
    const float* x    = (const float*)d_in[0];
    const float* expk = (const float*)d_in[1];
    float* y          = (float*)d_out;
    const int M = in_sizes[0] / N_COLS;        // 2048 rows
    idxct_kernel<<<dim3(M), dim3(NTHREADS), 0, stream>>>(x, expk, y);
}